// Round 8
// baseline (56.849 us; speedup 1.0000x reference)
//
#include <hip/hip_runtime.h>

// Problem constants (B=4, S=4096, DM=1024, H=16, HD=64)
#define M_TOTAL 16384
#define DMODEL  1024
#define HDIM    64
#define NHEAD   16

typedef _Float16 half8 __attribute__((ext_vector_type(8)));
typedef float    f32x4 __attribute__((ext_vector_type(4)));
typedef float    f32x2 __attribute__((ext_vector_type(2)));

// ---------------------------------------------------------------------------
// Math note: scores[b,s,h,g] = q.k is constant over g (k is broadcast over the
// head axis) -> softmax exactly uniform -> out rows = v -> final =
// (x@Wv+bv) @ (sum_h Wo[h*64+d][n]) + bo.  Wq/bq/Wk/bk are mathematically dead.
//
// Prep: WvT[d][k] = Wv[k][d]  (f16)          [64][1024]
//       WosumT[n][d] = sum_h Wo[h*64+d][n]   [1024][64] (f16)
// ---------------------------------------------------------------------------
__global__ __launch_bounds__(256) void prep_kernel(const float* __restrict__ Wv,
                                                   const float* __restrict__ Wo,
                                                   _Float16* __restrict__ WvT,
                                                   _Float16* __restrict__ WosumT) {
    const int t = blockIdx.x * 256 + threadIdx.x;   // 0..65535
    {   // WvT: consecutive t -> consecutive d -> coalesced Wv reads
        const int d = t & 63, k = t >> 6;
        WvT[d * DMODEL + k] = (_Float16)Wv[k * HDIM + d];
    }
    {   // WosumT: consecutive t -> consecutive n -> coalesced Wo reads
        const int n = t & 1023, d = t >> 10;
        float s = 0.f;
        #pragma unroll
        for (int h = 0; h < NHEAD; ++h) s += Wo[(h * HDIM + d) * DMODEL + n];
        WosumT[n * HDIM + d] = (_Float16)s;
    }
}

// ---------------------------------------------------------------------------
// Kernel A: V[16384][64] (f16) = X @ Wv + bv.   (proven ~14 us, round 6)
// 1024 blocks x 512 threads (8 waves). Wave w owns K in [w*128, w*128+128).
// Entire WvT slice (16 half8 = 64 VGPRs) preloaded; loop is pure {pack,4 MFMA}
// with all 8 X loads in flight. 8 partials LDS-reduced (+bv) -> f16.
// MFMA 16x16x32 f16: A lane l: A[l&15][(l>>4)*8+j]; B lane l: B[(l>>4)*8+j][l&15];
// C lane l reg j: row (l>>4)*4+j, col l&15.
// ---------------------------------------------------------------------------
#define VP_S 68   // row stride in words

__global__ __launch_bounds__(512, 4) void vproj_kernel(const float* __restrict__ X,
                                                       const float* __restrict__ bv,
                                                       const _Float16* __restrict__ WvT,
                                                       _Float16* __restrict__ V) {
    __shared__ float Vp[8][16][VP_S];   // 34816 B

    const int tid = threadIdx.x;
    const int l   = tid & 63;
    const int w   = tid >> 6;           // 0..7
    const int lr  = l & 15;
    const int lk  = l >> 4;
    const int m0  = blockIdx.x * 16;
    const int k0  = w * 128;

    // X loads first (HBM latency), all 8 in flight
    const float* xp = X + (size_t)(m0 + lr) * DMODEL + k0 + lk * 8;
    f32x4 xb[8];
    #pragma unroll
    for (int s = 0; s < 4; ++s) {
        xb[2 * s]     = *(const f32x4*)(xp + s * 32);
        xb[2 * s + 1] = *(const f32x4*)(xp + s * 32 + 4);
    }
    // B-fragments: register-resident for the whole loop (16 x half8)
    half8 Bf[4][4];
    #pragma unroll
    for (int n4 = 0; n4 < 4; ++n4)
        #pragma unroll
        for (int s = 0; s < 4; ++s)
            Bf[n4][s] = *(const half8*)&WvT[(size_t)(n4 * 16 + lr) * DMODEL + k0 + s * 32 + lk * 8];

    f32x4 acc[4] = {};
    #pragma unroll
    for (int s = 0; s < 4; ++s) {
        union { _Float16 h[8]; half8 v; } pk;
        #pragma unroll
        for (int j = 0; j < 4; ++j) {
            pk.h[j]     = (_Float16)xb[2 * s][j];
            pk.h[4 + j] = (_Float16)xb[2 * s + 1][j];
        }
        #pragma unroll
        for (int n4 = 0; n4 < 4; ++n4)
            acc[n4] = __builtin_amdgcn_mfma_f32_16x16x32_f16(pk.v, Bf[n4][s], acc[n4], 0, 0, 0);
    }
    #pragma unroll
    for (int n4 = 0; n4 < 4; ++n4)
        #pragma unroll
        for (int j = 0; j < 4; ++j)
            Vp[w][lk * 4 + j][n4 * 16 + lr] = acc[n4][j];
    __syncthreads();

    // reduce 8 partials; thread owns 2 consecutive elems of the 16x64 tile
    const int idx = tid * 2;
    const int r   = idx >> 6;
    const int c   = idx & 63;
    f32x2 s2 = {};
    #pragma unroll
    for (int p = 0; p < 8; ++p) s2 += *(const f32x2*)&Vp[p][r][c];
    s2 += *(const f32x2*)&bv[c];
    union { _Float16 h[2]; unsigned int u; } o;
    o.h[0] = (_Float16)s2[0];
    o.h[1] = (_Float16)s2[1];
    *(unsigned int*)&V[(size_t)(m0 + r) * HDIM + c] = o.u;
}

// ---------------------------------------------------------------------------
// Kernel B: Out[16384][1024] (f32) = V @ Wosum + bo.  (V already includes bv.)
// EXACT round-3 form (proven ~19 us by decomposition): 1024 blocks x 256 thr,
// NO min-waves hint (VGPR budget free -> no spill), barrier-free, no LDS.
// Wave w owns cols [w*256,(w+1)*256); B-frags JIT from L2 with unroll-4;
// scalar stores (L2 write-back assembles full lines; WRITE_SIZE was exactly
// 64 MB in rounds 3/4 -> no amplification).
// ---------------------------------------------------------------------------
__global__ __launch_bounds__(256) void oproj_kernel(const _Float16* __restrict__ V,
                                                    const float* __restrict__ bo,
                                                    const _Float16* __restrict__ WosumT,
                                                    float* __restrict__ Out) {
    const int tid = threadIdx.x;
    const int l   = tid & 63;
    const int w   = tid >> 6;
    const int lr  = l & 15;
    const int lk  = l >> 4;
    const int m0  = blockIdx.x * 16;

    const _Float16* vp = V + (size_t)(m0 + lr) * HDIM + lk * 8;
    const half8 a0 = *(const half8*)vp;
    const half8 a1 = *(const half8*)(vp + 32);

    #pragma unroll 4
    for (int nf = 0; nf < 16; ++nf) {
        const int n0 = w * 256 + nf * 16;
        const half8 b0 = *(const half8*)&WosumT[(size_t)(n0 + lr) * HDIM + lk * 8];
        const half8 b1 = *(const half8*)&WosumT[(size_t)(n0 + lr) * HDIM + 32 + lk * 8];
        f32x4 o = {};
        o = __builtin_amdgcn_mfma_f32_16x16x32_f16(a0, b0, o, 0, 0, 0);
        o = __builtin_amdgcn_mfma_f32_16x16x32_f16(a1, b1, o, 0, 0, 0);
        const float bov = bo[n0 + lr];
        #pragma unroll
        for (int j = 0; j < 4; ++j)
            Out[(size_t)(m0 + lk * 4 + j) * DMODEL + n0 + lr] = o[j] + bov;
    }
}

// ---------------------------------------------------------------------------
extern "C" void kernel_launch(void* const* d_in, const int* in_sizes, int n_in,
                              void* d_out, int out_size, void* d_ws, size_t ws_size,
                              hipStream_t stream) {
    const float* x  = (const float*)d_in[0];
    // d_in[1]=Wq, d_in[2]=bq, d_in[3]=Wk, d_in[4]=bk: mathematically dead.
    const float* Wv = (const float*)d_in[5];
    const float* bv = (const float*)d_in[6];
    const float* Wo = (const float*)d_in[7];
    const float* bo = (const float*)d_in[8];

    _Float16* WvT    = (_Float16*)d_ws;                            // 128 KB
    _Float16* WosumT = (_Float16*)((char*)d_ws + 64 * 1024 * 2);   // 128 KB
    _Float16* V      = (_Float16*)((char*)d_ws + 256 * 1024);      // 2 MB f16
    float*    out    = (float*)d_out;

    prep_kernel<<<256, 256, 0, stream>>>(Wv, Wo, WvT, WosumT);
    vproj_kernel<<<M_TOTAL / 16, 512, 0, stream>>>(x, bv, WvT, V);
    oproj_kernel<<<M_TOTAL / 16, 256, 0, stream>>>(V, bo, WosumT, out);
}

// Round 9
// 55.485 us; speedup vs baseline: 1.0246x; 1.0246x over previous
//
#include <hip/hip_runtime.h>

// Problem constants (B=4, S=4096, DM=1024, H=16, HD=64)
#define M_TOTAL 16384
#define DMODEL  1024
#define HDIM    64
#define NHEAD   16

typedef _Float16 half8 __attribute__((ext_vector_type(8)));
typedef float    f32x4 __attribute__((ext_vector_type(4)));
typedef float    f32x2 __attribute__((ext_vector_type(2)));

// ---------------------------------------------------------------------------
// Math note: scores[b,s,h,g] = q.k is constant over g (k is broadcast over the
// head axis) -> softmax exactly uniform -> out rows = v -> final =
// (x@Wv+bv) @ (sum_h Wo[h*64+d][n]) + bo.  Wq/bq/Wk/bk are mathematically dead.
//
// Prep: WvT[d][k] = Wv[k][d]  (f16)          [64][1024]
//       WosumT[n][d] = sum_h Wo[h*64+d][n]   [1024][64] (f16)
// ---------------------------------------------------------------------------
__global__ __launch_bounds__(256) void prep_kernel(const float* __restrict__ Wv,
                                                   const float* __restrict__ Wo,
                                                   _Float16* __restrict__ WvT,
                                                   _Float16* __restrict__ WosumT) {
    const int t = blockIdx.x * 256 + threadIdx.x;   // 0..65535
    {   // WvT: consecutive t -> consecutive d -> coalesced Wv reads
        const int d = t & 63, k = t >> 6;
        WvT[d * DMODEL + k] = (_Float16)Wv[k * HDIM + d];
    }
    {   // WosumT: consecutive t -> consecutive n -> coalesced Wo reads
        const int n = t & 1023, d = t >> 10;
        float s = 0.f;
        #pragma unroll
        for (int h = 0; h < NHEAD; ++h) s += Wo[(h * HDIM + d) * DMODEL + n];
        WosumT[n * HDIM + d] = (_Float16)s;
    }
}

// ---------------------------------------------------------------------------
// Single fused kernel. Grid 1024 x 512 thr (8 waves), lb(512,4) = 128 VGPR.
// Phase 1 (== round-6 vproj, the proven fast form): wave w owns K in
//   [w*128,+128): 8 X f32x4 loads issued first (HBM latency), entire WvT
//   slice register-resident (16 half8), loop = pure {pack, 4 MFMA}.
//   8 wave-partials -> LDS, reduce (+bv) -> Vh[16][64] f16 in LDS.
//   V never touches HBM.
// Phase 2 (round-3 compute shape, JIT-chain removed): wave w owns cols
//   [w*128,+128) as 2 halves of 64; per half preload 8 B-frags (32 VGPR,
//   one vmcnt group) then 4x{2 MFMA} back-to-back; scalar stores + bo
//   (WRITE_SIZE was exactly 64 MB with this store shape in r3/r4).
// 2 barriers total.
// MFMA 16x16x32 f16: A lane l: A[l&15][(l>>4)*8+j]; B lane l: B[(l>>4)*8+j][l&15];
// C lane l reg j: row (l>>4)*4+j, col l&15.
// ---------------------------------------------------------------------------
#define VP_S 68   // partial-buffer row stride (f32 words)
#define VH_S 72   // Vh row stride (halves): 144B rows -> banks rotate by 4

__global__ __launch_bounds__(512, 4) void mqa_fused(const float* __restrict__ X,
                                                    const float* __restrict__ bv,
                                                    const float* __restrict__ bo,
                                                    const _Float16* __restrict__ WvT,
                                                    const _Float16* __restrict__ WosumT,
                                                    float* __restrict__ Out) {
    __shared__ float    Vp[8][16][VP_S];    // 34816 B
    __shared__ _Float16 Vh[16 * VH_S];      //  2304 B

    const int tid = threadIdx.x;
    const int l   = tid & 63;
    const int w   = tid >> 6;           // 0..7
    const int lr  = l & 15;
    const int lk  = l >> 4;
    const int m0  = blockIdx.x * 16;
    const int k0  = w * 128;

    // ---- Phase 1: X loads first (HBM latency), all 8 in flight ----
    const float* xp = X + (size_t)(m0 + lr) * DMODEL + k0 + lk * 8;
    f32x4 xb[8];
    #pragma unroll
    for (int s = 0; s < 4; ++s) {
        xb[2 * s]     = *(const f32x4*)(xp + s * 32);
        xb[2 * s + 1] = *(const f32x4*)(xp + s * 32 + 4);
    }
    // B-fragments: register-resident for the whole loop (16 x half8)
    half8 Bf[4][4];
    #pragma unroll
    for (int n4 = 0; n4 < 4; ++n4)
        #pragma unroll
        for (int s = 0; s < 4; ++s)
            Bf[n4][s] = *(const half8*)&WvT[(size_t)(n4 * 16 + lr) * DMODEL + k0 + s * 32 + lk * 8];

    f32x4 acc[4] = {};
    #pragma unroll
    for (int s = 0; s < 4; ++s) {
        union { _Float16 h[8]; half8 v; } pk;
        #pragma unroll
        for (int j = 0; j < 4; ++j) {
            pk.h[j]     = (_Float16)xb[2 * s][j];
            pk.h[4 + j] = (_Float16)xb[2 * s + 1][j];
        }
        #pragma unroll
        for (int n4 = 0; n4 < 4; ++n4)
            acc[n4] = __builtin_amdgcn_mfma_f32_16x16x32_f16(pk.v, Bf[n4][s], acc[n4], 0, 0, 0);
    }
    #pragma unroll
    for (int n4 = 0; n4 < 4; ++n4)
        #pragma unroll
        for (int j = 0; j < 4; ++j)
            Vp[w][lk * 4 + j][n4 * 16 + lr] = acc[n4][j];
    __syncthreads();

    // ---- Reduce 8 partials (+bv) -> Vh f16 in LDS; thread owns 2 elems ----
    {
        const int idx = tid * 2;
        const int r   = idx >> 6;
        const int c   = idx & 63;
        f32x2 s2 = {};
        #pragma unroll
        for (int p = 0; p < 8; ++p) s2 += *(const f32x2*)&Vp[p][r][c];
        s2 += *(const f32x2*)&bv[c];
        union { _Float16 h[2]; unsigned int u; } o;
        o.h[0] = (_Float16)s2[0];
        o.h[1] = (_Float16)s2[1];
        *(unsigned int*)&Vh[r * VH_S + c] = o.u;
    }
    __syncthreads();

    // ---- Phase 2: Out cols [w*128,+128) in 2 halves of 64 ----
    const half8 a0 = *(const half8*)&Vh[lr * VH_S + lk * 8];
    const half8 a1 = *(const half8*)&Vh[lr * VH_S + 32 + lk * 8];

    #pragma unroll
    for (int h = 0; h < 2; ++h) {
        const int cb = w * 128 + h * 64;
        half8 B2[4][2];
        #pragma unroll
        for (int t = 0; t < 4; ++t) {
            const _Float16* wb = &WosumT[(size_t)(cb + t * 16 + lr) * HDIM];
            B2[t][0] = *(const half8*)(wb + lk * 8);
            B2[t][1] = *(const half8*)(wb + 32 + lk * 8);
        }
        #pragma unroll
        for (int t = 0; t < 4; ++t) {
            f32x4 o = {};
            o = __builtin_amdgcn_mfma_f32_16x16x32_f16(a0, B2[t][0], o, 0, 0, 0);
            o = __builtin_amdgcn_mfma_f32_16x16x32_f16(a1, B2[t][1], o, 0, 0, 0);
            const float bov = bo[cb + t * 16 + lr];
            #pragma unroll
            for (int j = 0; j < 4; ++j)
                Out[(size_t)(m0 + lk * 4 + j) * DMODEL + cb + t * 16 + lr] = o[j] + bov;
        }
    }
}

// ---------------------------------------------------------------------------
extern "C" void kernel_launch(void* const* d_in, const int* in_sizes, int n_in,
                              void* d_out, int out_size, void* d_ws, size_t ws_size,
                              hipStream_t stream) {
    const float* x  = (const float*)d_in[0];
    // d_in[1]=Wq, d_in[2]=bq, d_in[3]=Wk, d_in[4]=bk: mathematically dead.
    const float* Wv = (const float*)d_in[5];
    const float* bv = (const float*)d_in[6];
    const float* Wo = (const float*)d_in[7];
    const float* bo = (const float*)d_in[8];

    _Float16* WvT    = (_Float16*)d_ws;                            // 128 KB
    _Float16* WosumT = (_Float16*)((char*)d_ws + 64 * 1024 * 2);   // 128 KB
    float*    out    = (float*)d_out;

    prep_kernel<<<256, 256, 0, stream>>>(Wv, Wo, WvT, WosumT);
    mqa_fused<<<M_TOTAL / 16, 512, 0, stream>>>(x, bv, bo, WvT, WosumT, out);
}